// Round 16
// baseline (5599.598 us; speedup 1.0000x reference)
//
#include <hip/hip_runtime.h>
#include <math.h>

// ---------------------------------------------------------------------------
// SRRNN: state-regularized GRU.  B=64, S=512, I=256, H=512, K=256, TEMP=1.
//
// Round 16: R14 structure + asm-pinned register weights.
//  - R8/R14 post-mortem: the allocator CHOSE 128 VGPRs and rematerialized
//    the 48-float4 weight loads from L2 every step (~96 dependent loads per
//    GEMM = the R14 regression), despite launch_bounds permitting 256.
//  - Fix: empty asm volatile("" : "+v"(...)) pins all 192 weight floats
//    after the one-time load -> rematerialization illegal, values must
//    stay in VGPRs. 192 weights + ~45 working = ~240 < 256 cap (8 waves/CU).
//  - Structure = R14: 32 groups x 8 CUs, NB=2, DPC=64; poll = 8 sources
//    (2048 transactions/CU/step, 4x fewer than R12); sign-bit epoch comm
//    (R12-proven); wave-split weights (0-3: W_ih, 4-7: SWT); phases:
//    A gates||stage, B dist+store, C gi||poll, D softmax, E h_new||gh.
// ---------------------------------------------------------------------------

#define B_ 64
#define S_ 512
#define I_ 256
#define H_ 512
#define K_ 256
#define G3H 1536
#define NGRP 32
#define GCU 8
#define NB 2
#define DPC 64
#define TPB 512
#define SPIN_MAX (1 << 15)

// workspace layout (bytes)
#define WS_SWT 4096
#define WS_SWT_SZ (G3H * K_ * 4)                       // 1572864
#define WS_GH0 (WS_SWT + WS_SWT_SZ)
#define WS_GH0_SZ (B_ * G3H * 4)                       // 393216
#define WS_PK (WS_GH0 + WS_GH0_SZ)                     // 1970176 (8B aligned)
#define WS_PK_SZ (2 * NGRP * NB * GCU * 128 * 8)       // 1048576

// LDS float offsets
#define L_ST 0               // s_T[64][256]   j-major (dist)
#define L_SSL 16384          // s_sl[256][68]  k-major (h_new)
#define L_XCH 33792          // x_ch [2][16][20]
#define L_PCH 34432          // p_ch [2][16][20]
#define L_GI 35072           // gi_sl [2][192]
#define L_GH 35456           // gh_sl [2][192]
#define L_HC 35840           // hc_sl [2][64]
#define L_HP 35968           // hp_sl [2][64]
#define L_BIH 36096          // [192]
#define L_BHH 36288          // [192]
#define L_D 36480            // d_sl [2][256]
#define SMEM_BYTES 148480    // 1 block/CU

#define OUT_OFF_HN (B_ * S_ * H_)
#define OUT_OFF_P (OUT_OFF_HN + B_ * H_)

#define AGENT __HIP_MEMORY_SCOPE_AGENT
#define RLX __ATOMIC_RELAXED
#define SGNMASK 0x8000000080000000ull

// ---------------------------------------------------------------------------
__global__ void kernel_swt(const float* __restrict__ Whh,
                           const float* __restrict__ states,
                           float* __restrict__ SWT) {
  int r0 = blockIdx.x * 8;
  int k = threadIdx.x;  // 0..255
  const float* sr = states + (size_t)k * H_;
  float acc[8];
#pragma unroll
  for (int q = 0; q < 8; ++q) acc[q] = 0.f;
  for (int j = 0; j < H_; ++j) {
    float sv = sr[j];
#pragma unroll
    for (int q = 0; q < 8; ++q) acc[q] += Whh[(size_t)(r0 + q) * H_ + j] * sv;
  }
#pragma unroll
  for (int q = 0; q < 8; ++q) SWT[(size_t)(r0 + q) * K_ + k] = acc[q];
}

__global__ void kernel_gh0(const float* __restrict__ Whh,
                           const float* __restrict__ h0,
                           float* __restrict__ Gh0) {
  int b = blockIdx.x;
  int tid = threadIdx.x;  // 256
  __shared__ float h[H_];
  for (int e = tid; e < H_; e += 256) h[e] = h0[(size_t)b * H_ + e];
  __syncthreads();
  for (int r = tid; r < G3H; r += 256) {
    const float* wr = Whh + (size_t)r * H_;
    float acc = 0.f;
    for (int j = 0; j < H_; ++j) acc += wr[j] * h[j];
    Gh0[(size_t)b * G3H + r] = acc;
  }
}

// ---------------------------------------------------------------------------
__device__ __forceinline__ float dot4(float4 a, float4 b) {
  return a.x * b.x + a.y * b.y + a.z * b.z + a.w * b.w;
}
__device__ __forceinline__ unsigned long long pk_pack(float lo, float hi,
                                                      unsigned sb) {
  return ((unsigned long long)(__float_as_uint(hi) | sb) << 32) |
         (unsigned long long)(__float_as_uint(lo) | sb);
}
__device__ __forceinline__ unsigned long long tload(
    const unsigned long long* p) {
  return __hip_atomic_load(p, RLX, AGENT);
}
__device__ __forceinline__ void tstore(unsigned long long* p,
                                       unsigned long long w) {
  __hip_atomic_store(p, w, RLX, AGENT);
}

// 192-row gate GEMM for 2 batches; weights in registers (12 rows x 16k)
__device__ __forceinline__ void gemm192(const float* inb, float* outb,
                                        const float4 (*w)[4], int rowblk,
                                        int kseg) {
#pragma unroll
  for (int b = 0; b < 2; ++b) {
    const float4* xp = (const float4*)(inb + (b * 16 + kseg) * 20);
    float4 x0 = xp[0], x1 = xp[1], x2 = xp[2], x3 = xp[3];
    float acc[12];
#pragma unroll
    for (int i = 0; i < 12; ++i)
      acc[i] = dot4(w[i][0], x0) + dot4(w[i][1], x1) + dot4(w[i][2], x2) +
               dot4(w[i][3], x3);
#pragma unroll
    for (int i = 0; i < 12; ++i) {
      float v = acc[i];
      v += __shfl_xor(v, 1); v += __shfl_xor(v, 2);
      v += __shfl_xor(v, 4); v += __shfl_xor(v, 8);
      acc[i] = v;
    }
    if (kseg == 0) {
#pragma unroll
      for (int i = 0; i < 12; ++i) outb[b * 192 + rowblk * 12 + i] = acc[i];
    }
  }
}

// ---------------------------------------------------------------------------
__global__ __launch_bounds__(TPB, 2) void srrnn_main(
    const float* __restrict__ input, const float* __restrict__ h0,
    const float* __restrict__ W_ih, const float* __restrict__ bias_ih,
    const float* __restrict__ bias_hh, const float* __restrict__ states,
    const float* __restrict__ SWT, const float* __restrict__ Gh0,
    unsigned long long* __restrict__ pk,
    float* __restrict__ out, float* __restrict__ hn,
    float* __restrict__ probs) {
  const int tid = threadIdx.x;
  const int g = blockIdx.x >> 3;   // group 0..31
  const int cu = blockIdx.x & 7;   // CU in group
  const int d0 = cu << 6;          // owned dim base (64 dims)

  extern __shared__ float smem[];
  float* s_T = smem + L_ST;        // [j][256]
  float* s_sl = smem + L_SSL;      // [k][68]
  float* x_ch = smem + L_XCH;      // [2][16][20]
  float* p_ch = smem + L_PCH;      // [2][16][20]
  float* gi_sl = smem + L_GI;
  float* gh_sl = smem + L_GH;
  float* hc_sl = smem + L_HC;
  float* hp_sl = smem + L_HP;
  float* bih_sl = smem + L_BIH;
  float* bhh_sl = smem + L_BHH;
  float* d_sl = smem + L_D;

  const int wv = tid >> 6, lane = tid & 63;
  const int rowblk = (tid & 255) >> 4;   // 0..15 within wave-group
  const int kseg = tid & 15;

  // ---- setup ----
  for (int e = tid; e < K_ * DPC; e += TPB) {
    int k = e >> 6, j = e & 63;
    float v = states[((size_t)k << 9) + d0 + j];
    s_T[j * 256 + k] = v;
    s_sl[k * 68 + j] = v;
  }
  if (tid < 192) {
    int grow = ((tid >> 6) << 9) + d0 + (tid & 63);
    bih_sl[tid] = bias_ih[grow];
    bhh_sl[tid] = bias_hh[grow];
  }
  if (tid < 128) {
    int b = tid >> 6, j = tid & 63;
    hp_sl[(b << 6) + j] = h0[((size_t)(g * NB + b) << 9) + d0 + j];
  }
  if (tid < 384) {
    int b = tid / 192, r = tid % 192;
    int grow = ((r >> 6) << 9) + d0 + (r & 63);
    gh_sl[b * 192 + r] = Gh0[(size_t)(g * NB + b) * G3H + grow];
  }
  // unified weight fragment: waves 0-3 hold W_ih, waves 4-7 hold SWT
  float4 w[12][4];
  {
    const float* Wsrc = (tid < 256) ? W_ih : SWT;
#pragma unroll
    for (int i = 0; i < 12; ++i) {
      int r = rowblk * 12 + i;  // 0..191
      int grow = ((r >> 6) << 9) + d0 + (r & 63);
      const float4* src =
          (const float4*)(Wsrc + (size_t)grow * K_ + (kseg << 4));
      w[i][0] = src[0]; w[i][1] = src[1]; w[i][2] = src[2]; w[i][3] = src[3];
    }
  }
  // PIN the weights in registers: empty asm makes the values opaque, so the
  // allocator cannot rematerialize the loads inside the t-loop (R8/R14 bug).
#pragma unroll
  for (int i = 0; i < 12; ++i)
#pragma unroll
    for (int c = 0; c < 4; ++c)
      asm volatile("" : "+v"(w[i][c].x), "+v"(w[i][c].y), "+v"(w[i][c].z),
                        "+v"(w[i][c].w));
  __syncthreads();

  // ---- pre-loop: stage x(0) chunked, gi(0) ----
  if (tid < 128) {
    int b = tid >> 6, c = tid & 63;
    float4 v = *((const float4*)(input + ((size_t)(g * NB + b) * S_) * I_) + c);
    *(float4*)(x_ch + (b * 16 + (c >> 2)) * 20 + ((c & 3) << 2)) = v;
  }
  __syncthreads();
  if (tid < 256) gemm192(x_ch, gi_sl, w, rowblk, kseg);
  __syncthreads();

  for (int t = 0; t < S_; ++t) {
    const unsigned sb = (unsigned)((t >> 1) & 1) << 31;
    const unsigned long long expect =
        ((unsigned long long)sb << 32) | (unsigned long long)sb;
    unsigned long long* pks = pk + ((size_t)(t & 1) << 16);  // slot base

    // ---- A: gates (tid<128) || stage x(t+1) (tid>=384) ----
    if (tid < 128) {
      int b = tid >> 6, j = tid & 63;
      float gir = gi_sl[b * 192 + j] + bih_sl[j];
      float giz = gi_sl[b * 192 + 64 + j] + bih_sl[64 + j];
      float gin = gi_sl[b * 192 + 128 + j] + bih_sl[128 + j];
      float ghr = gh_sl[b * 192 + j] + bhh_sl[j];
      float ghz = gh_sl[b * 192 + 64 + j] + bhh_sl[64 + j];
      float ghn = gh_sl[b * 192 + 128 + j] + bhh_sl[128 + j];
      float r = 1.f / (1.f + expf(-(gir + ghr)));
      float z = 1.f / (1.f + expf(-(giz + ghz)));
      float n = tanhf(gin + r * ghn);
      hc_sl[(b << 6) + j] = (1.f - z) * n + z * hp_sl[(b << 6) + j];
    } else if (tid >= 384 && t + 1 < S_) {
      int s = tid - 384;
      int b = s >> 6, c = s & 63;
      float4 v = *((const float4*)(input +
                   ((size_t)(g * NB + b) * S_ + (t + 1)) * I_) + c);
      *(float4*)(x_ch + (b * 16 + (c >> 2)) * 20 + ((c & 3) << 2)) = v;
    }
    __syncthreads();

    // ---- B: dist partials over 64 dims -> packed sign-tagged stores ----
    {
      int b = tid >> 8;              // 0..1
      int sub = tid & 255;
      int k4 = sub >> 2;             // float4-of-k index 0..63
      int jq = sub & 3;              // j quarter (16 dims each)
      const float* hb = hc_sl + (b << 6) + (jq << 4);
      const float4* sp = (const float4*)(s_T + ((jq << 4) * 256) + (k4 << 2));
      float ax = 0.f, ay = 0.f, az = 0.f, aw = 0.f;
#pragma unroll
      for (int jj = 0; jj < 16; ++jj) {
        float4 s4 = sp[jj * 64];
        float hv = hb[jj];
        float e;
        e = hv - s4.x; ax += e * e;
        e = hv - s4.y; ay += e * e;
        e = hv - s4.z; az += e * e;
        e = hv - s4.w; aw += e * e;
      }
      ax += __shfl_xor(ax, 1); ax += __shfl_xor(ax, 2);
      ay += __shfl_xor(ay, 1); ay += __shfl_xor(ay, 2);
      az += __shfl_xor(az, 1); az += __shfl_xor(az, 2);
      aw += __shfl_xor(aw, 1); aw += __shfl_xor(aw, 2);
      if (jq == 0) {
        unsigned long long* dst =
            pks + ((((size_t)(g * NB + b) << 3) + cu) << 7) + (k4 << 1);
        tstore(dst + 0, pk_pack(ax, ay, sb));
        tstore(dst + 1, pk_pack(az, aw, sb));
      }
    }

    // ---- C: gi(t+1) GEMM (waves 0-3) || poll 8 sources (waves 4-7) ----
    if (tid < 256) {
      if (t + 1 < S_) gemm192(x_ch, gi_sl, w, rowblk, kseg);
    } else {
      int sub = tid - 256;
      int b = sub >> 7, wp = sub & 127;
      const unsigned long long* base =
          pks + (((size_t)(g * NB + b) << 3) << 7) + wp;
      unsigned long long wd[GCU];
#pragma unroll
      for (int s = 0; s < GCU; ++s) wd[s] = tload(base + (s << 7));
#pragma unroll
      for (int s = 0; s < GCU; ++s) {
        int it = 0;
        while ((wd[s] & SGNMASK) != expect && ++it < SPIN_MAX)
          wd[s] = tload(base + (s << 7));
      }
      float dlo = 0.f, dhi = 0.f;
#pragma unroll
      for (int s = 0; s < GCU; ++s) {
        dlo += __uint_as_float((unsigned)(wd[s] & 0x7fffffffu));
        dhi += __uint_as_float((unsigned)((wd[s] >> 32) & 0x7fffffffu));
      }
      d_sl[(b << 8) + (wp << 1) + 0] = dlo;
      d_sl[(b << 8) + (wp << 1) + 1] = dhi;
    }
    __syncthreads();

    // ---- D: softmax (waves 0-1, wave = batch) -> p_ch chunked + probs ----
    if (wv < NB) {
      int b = wv;
      const float* db = d_sl + (b << 8);
      float dd0 = db[lane], dd1 = db[lane + 64], dd2 = db[lane + 128],
            dd3 = db[lane + 192];
      float mn = fminf(fminf(dd0, dd1), fminf(dd2, dd3));
#pragma unroll
      for (int off = 32; off >= 1; off >>= 1) mn = fminf(mn, __shfl_xor(mn, off));
      float e0 = expf(mn - dd0), e1 = expf(mn - dd1), e2 = expf(mn - dd2),
            e3 = expf(mn - dd3);
      float s = (e0 + e1) + (e2 + e3);
#pragma unroll
      for (int off = 32; off >= 1; off >>= 1) s += __shfl_xor(s, off);
      float inv = 1.f / s;
      e0 *= inv; e1 *= inv; e2 *= inv; e3 *= inv;
      int hi = lane >> 4, lo = lane & 15;
      p_ch[(b * 16 + hi + 0) * 20 + lo] = e0;
      p_ch[(b * 16 + hi + 4) * 20 + lo] = e1;
      p_ch[(b * 16 + hi + 8) * 20 + lo] = e2;
      p_ch[(b * 16 + hi + 12) * 20 + lo] = e3;
      if (cu == 0) {
        float* pr = probs + (((size_t)(g * NB + b) * S_ + t) << 8);
        pr[lane] = e0; pr[lane + 64] = e1; pr[lane + 128] = e2;
        pr[lane + 192] = e3;
      }
    }
    __syncthreads();

    // ---- E: h_new (waves 0-3) || gh(t+1) GEMM (waves 4-7) ----
    if (tid < 256) {
      int b = tid >> 7;
      int sub = tid & 127;
      int j = sub >> 1, kq2 = sub & 1;
      float a = 0.f;
#pragma unroll
      for (int i = 0; i < 16; ++i) {
        const float4* pp = (const float4*)(p_ch + (b * 16 + i) * 20) + kq2 * 2;
        float4 pa = pp[0], pb2 = pp[1];
        int k = (i << 4) + (kq2 << 3);
        a += pa.x * s_sl[(k + 0) * 68 + j] + pa.y * s_sl[(k + 1) * 68 + j] +
             pa.z * s_sl[(k + 2) * 68 + j] + pa.w * s_sl[(k + 3) * 68 + j];
        a += pb2.x * s_sl[(k + 4) * 68 + j] + pb2.y * s_sl[(k + 5) * 68 + j] +
             pb2.z * s_sl[(k + 6) * 68 + j] + pb2.w * s_sl[(k + 7) * 68 + j];
      }
      a += __shfl_xor(a, 1);
      if (kq2 == 0) {
        hp_sl[(b << 6) + j] = a;
        out[(((size_t)(g * NB + b) * S_ + t) << 9) + d0 + j] = a;
      }
    } else if (t + 1 < S_) {
      gemm192(p_ch, gh_sl, w, rowblk, kseg);
    }
    __syncthreads();
  }

  // ---- final hidden state ----
  if (tid < 128) {
    int b = tid >> 6, j = tid & 63;
    hn[((size_t)(g * NB + b) << 9) + d0 + j] = hp_sl[(b << 6) + j];
  }
}

// ---------------------------------------------------------------------------
extern "C" void kernel_launch(void* const* d_in, const int* in_sizes, int n_in,
                              void* d_out, int out_size, void* d_ws,
                              size_t ws_size, hipStream_t stream) {
  const float* input = (const float*)d_in[0];
  const float* h0 = (const float*)d_in[1];
  const float* W_ih = (const float*)d_in[2];
  const float* W_hh = (const float*)d_in[3];
  const float* bias_ih = (const float*)d_in[4];
  const float* bias_hh = (const float*)d_in[5];
  const float* states = (const float*)d_in[6];
  float* out = (float*)d_out;

  char* ws = (char*)d_ws;
  float* SWT = (float*)(ws + WS_SWT);
  float* Gh0 = (float*)(ws + WS_GH0);
  unsigned long long* pk = (unsigned long long*)(ws + WS_PK);

  // 0x80 bytes -> every packed float negative -> never matches the expected
  // sign pattern at t=0/1; kills cross-replay staleness.
  (void)hipMemsetAsync(ws + WS_PK, 0x80, WS_PK_SZ, stream);
  kernel_swt<<<G3H / 8, 256, 0, stream>>>(W_hh, states, SWT);
  kernel_gh0<<<B_, 256, 0, stream>>>(W_hh, h0, Gh0);

  (void)hipFuncSetAttribute(reinterpret_cast<const void*>(srrnn_main),
                            hipFuncAttributeMaxDynamicSharedMemorySize,
                            SMEM_BYTES);
  srrnn_main<<<NGRP * GCU, TPB, SMEM_BYTES, stream>>>(
      input, h0, W_ih, bias_ih, bias_hh, states, SWT, Gh0, pk,
      out, out + OUT_OFF_HN, out + OUT_OFF_P);
}

// Round 17
// 4825.817 us; speedup vs baseline: 1.1603x; 1.1603x over previous
//
#include <hip/hip_runtime.h>
#include <math.h>

// ---------------------------------------------------------------------------
// SRRNN: state-regularized GRU.  B=64, S=512, I=256, H=512, K=256, TEMP=1.
//
// Round 17: hoisted gi (reference-style) + GCU=8 + R12 comm.
//  - gi_all = input @ W_ih^T precomputed by kernel_gi (one bandwidth GEMM).
//    The persistent kernel loads 1.5KB/step/CU instead of running the gi
//    GEMM — and needs NO W_ih registers.
//  - 32 groups x 8 CUs, NB=2, DPC=64 (192 SWT rows/CU). SWT split across
//    half-blocks: waves 0-3 rows 0-95, waves 4-7 rows 96-191 -> 24 float4
//    per thread (the allocator-proven size; 48 is refused, R8/R14/R16).
//  - Poll: 8 sources, split by source-half over all 512 threads -> 4 serial
//    8B atomic loads per thread (R12 had 16).
//  - Comm protocol = R12 verbatim: 2 slots (t&1), sign epoch (t>>1)&1,
//    packed 2xf32 per 64-bit word, memset(0x80) per launch, bounded spins.
// ---------------------------------------------------------------------------

#define B_ 64
#define S_ 512
#define I_ 256
#define H_ 512
#define K_ 256
#define G3H 1536
#define NGRP 32
#define GCU 8
#define NB 2
#define DPC 64
#define TPB 512
#define SPIN_MAX (1 << 15)

// workspace layout (bytes)
#define WS_SWT 4096
#define WS_SWT_SZ (G3H * K_ * 4)                       // 1572864
#define WS_GH0 (WS_SWT + WS_SWT_SZ)
#define WS_GH0_SZ (B_ * G3H * 4)                       // 393216
#define WS_PK (WS_GH0 + WS_GH0_SZ)                     // 1970176 (8B aligned)
#define WS_PK_SZ (2 * NGRP * NB * GCU * 128 * 8)       // 1048576
#define WS_GI (WS_PK + WS_PK_SZ)                       // 3018752
#define WS_GI_SZ ((size_t)B_ * S_ * G3H * 4)           // 201326592

// LDS float offsets
#define L_ST 0               // s_T[64][256]   j-major (dist)
#define L_SSL 16384          // s_sl[256][68]  k-major (h_new)
#define L_PCH 33792          // p_ch [2][16][20]
#define L_GI2 34432          // gi2 [2 slots][2 b][192]
#define L_GH 35200           // gh_sl [2][192]
#define L_HC 35584           // hc_sl [2][64]
#define L_HP 35712           // hp_sl [2][64]
#define L_BIH 35840          // [192]
#define L_BHH 36032          // [192]
#define L_DA 36224           // d_a [2][256]
#define L_DB 36736           // d_b [2][256]
#define SMEM_BYTES 149504    // 37248 floats; 1 block/CU

#define OUT_OFF_HN (B_ * S_ * H_)
#define OUT_OFF_P (OUT_OFF_HN + B_ * H_)

#define AGENT __HIP_MEMORY_SCOPE_AGENT
#define RLX __ATOMIC_RELAXED
#define SGNMASK 0x8000000080000000ull

// ---------------------------------------------------------------------------
__global__ void kernel_swt(const float* __restrict__ Whh,
                           const float* __restrict__ states,
                           float* __restrict__ SWT) {
  int r0 = blockIdx.x * 8;
  int k = threadIdx.x;  // 0..255
  const float* sr = states + (size_t)k * H_;
  float acc[8];
#pragma unroll
  for (int q = 0; q < 8; ++q) acc[q] = 0.f;
  for (int j = 0; j < H_; ++j) {
    float sv = sr[j];
#pragma unroll
    for (int q = 0; q < 8; ++q) acc[q] += Whh[(size_t)(r0 + q) * H_ + j] * sv;
  }
#pragma unroll
  for (int q = 0; q < 8; ++q) SWT[(size_t)(r0 + q) * K_ + k] = acc[q];
}

__global__ void kernel_gh0(const float* __restrict__ Whh,
                           const float* __restrict__ h0,
                           float* __restrict__ Gh0) {
  int b = blockIdx.x;
  int tid = threadIdx.x;  // 256
  __shared__ float h[H_];
  for (int e = tid; e < H_; e += 256) h[e] = h0[(size_t)b * H_ + e];
  __syncthreads();
  for (int r = tid; r < G3H; r += 256) {
    const float* wr = Whh + (size_t)r * H_;
    float acc = 0.f;
    for (int j = 0; j < H_; ++j) acc += wr[j] * h[j];
    Gh0[(size_t)b * G3H + r] = acc;
  }
}

// gi_all[b][t][1536] = input[b][t] @ W_ih^T.  grid (32 tchunks, 64 b), 256 thr.
__global__ void kernel_gi(const float* __restrict__ input,
                          const float* __restrict__ W_ih,
                          float* __restrict__ gi_all) {
  const int t0 = blockIdx.x * 16;
  const int b = blockIdx.y;
  const int tid = threadIdx.x;
  __shared__ float x_s[16 * 260];
  for (int e = tid; e < 16 * 256; e += 256) {
    int tt = e >> 8, k = e & 255;
    x_s[tt * 260 + k] = input[(((size_t)b * S_) + (t0 + tt)) * I_ + k];
  }
  __syncthreads();
  for (int r = tid; r < G3H; r += 256) {
    const float* wr = W_ih + (size_t)r * I_;
    float acc[16];
#pragma unroll
    for (int tt = 0; tt < 16; ++tt) acc[tt] = 0.f;
    for (int k = 0; k < I_; ++k) {
      float w = wr[k];
#pragma unroll
      for (int tt = 0; tt < 16; ++tt) acc[tt] += w * x_s[tt * 260 + k];
    }
#pragma unroll
    for (int tt = 0; tt < 16; ++tt)
      gi_all[(((size_t)b * S_) + (t0 + tt)) * G3H + r] = acc[tt];
  }
}

// ---------------------------------------------------------------------------
__device__ __forceinline__ float dot4(float4 a, float4 b) {
  return a.x * b.x + a.y * b.y + a.z * b.z + a.w * b.w;
}
__device__ __forceinline__ unsigned long long pk_pack(float lo, float hi,
                                                      unsigned sb) {
  return ((unsigned long long)(__float_as_uint(hi) | sb) << 32) |
         (unsigned long long)(__float_as_uint(lo) | sb);
}
__device__ __forceinline__ unsigned long long tload(
    const unsigned long long* p) {
  return __hip_atomic_load(p, RLX, AGENT);
}
__device__ __forceinline__ void tstore(unsigned long long* p,
                                       unsigned long long w) {
  __hip_atomic_store(p, w, RLX, AGENT);
}

// ---------------------------------------------------------------------------
__global__ __launch_bounds__(TPB, 2) void srrnn_main(
    const float* __restrict__ gi_all, const float* __restrict__ h0,
    const float* __restrict__ bias_ih, const float* __restrict__ bias_hh,
    const float* __restrict__ states, const float* __restrict__ SWT,
    const float* __restrict__ Gh0, unsigned long long* __restrict__ pk,
    float* __restrict__ out, float* __restrict__ hn,
    float* __restrict__ probs) {
  const int tid = threadIdx.x;
  const int g = blockIdx.x >> 3;   // group 0..31
  const int cu = blockIdx.x & 7;   // CU in group
  const int d0 = cu << 6;          // owned dim base (64 dims)

  extern __shared__ float smem[];
  float* s_T = smem + L_ST;        // [j][256]
  float* s_sl = smem + L_SSL;      // [k][68]
  float* p_ch = smem + L_PCH;      // [2][16][20]
  float* gi2 = smem + L_GI2;       // [2][2][192]
  float* gh_sl = smem + L_GH;      // [2][192]
  float* hc_sl = smem + L_HC;
  float* hp_sl = smem + L_HP;
  float* bih_sl = smem + L_BIH;
  float* bhh_sl = smem + L_BHH;
  float* d_a = smem + L_DA;
  float* d_b = smem + L_DB;

  const int wv = tid >> 6, lane = tid & 63;
  const int half = tid >> 8;             // SWT row-half owner
  const int rowblk = (tid & 255) >> 4;   // 0..15
  const int kseg = tid & 15;

  // ---- setup ----
  for (int e = tid; e < K_ * DPC; e += TPB) {
    int k = e >> 6, j = e & 63;
    float v = states[((size_t)k << 9) + d0 + j];
    s_T[j * 256 + k] = v;
    s_sl[k * 68 + j] = v;
  }
  if (tid < 192) {
    int grow = ((tid >> 6) << 9) + d0 + (tid & 63);
    bih_sl[tid] = bias_ih[grow];
    bhh_sl[tid] = bias_hh[grow];
  }
  if (tid < 128) {
    int b = tid >> 6, j = tid & 63;
    hp_sl[(b << 6) + j] = h0[((size_t)(g * NB + b) << 9) + d0 + j];
  }
  if (tid < 384) {
    int b = tid / 192, r = tid % 192;
    int grow = ((r >> 6) << 9) + d0 + (r & 63);
    gh_sl[b * 192 + r] = Gh0[(size_t)(g * NB + b) * G3H + grow];
  }
  if (tid < 96) {  // gi(0) -> slot 0
    int b = tid / 48, rr = tid % 48;
    int gate = rr >> 4, pos = rr & 15;
    float4 v = *(const float4*)(gi_all +
        ((size_t)(g * NB + b) * S_) * G3H + (gate << 9) + d0 + (pos << 2));
    *(float4*)(gi2 + b * 192 + (gate << 6) + (pos << 2)) = v;
  }
  // SWT fragment: half h owns local rows 96h..96h+95; 6 rows x 16 k/thread
  float4 w[6][4];
#pragma unroll
  for (int i = 0; i < 6; ++i) {
    int r = half * 96 + rowblk * 6 + i;  // 0..191
    int grow = ((r >> 6) << 9) + d0 + (r & 63);
    const float4* src = (const float4*)(SWT + (size_t)grow * K_ + (kseg << 4));
    w[i][0] = src[0]; w[i][1] = src[1]; w[i][2] = src[2]; w[i][3] = src[3];
  }
  __syncthreads();

  for (int t = 0; t < S_; ++t) {
    const unsigned sb = (unsigned)((t >> 1) & 1) << 31;
    const unsigned long long expect =
        ((unsigned long long)sb << 32) | (unsigned long long)sb;
    unsigned long long* pks = pk + ((size_t)(t & 1) << 16);  // slot base
    const float* gi_cur = gi2 + (t & 1) * 384;

    // ---- A: gates (tid<128) || gi(t+1) load (tid 256-351) ----
    if (tid < 128) {
      int b = tid >> 6, j = tid & 63;
      float gir = gi_cur[b * 192 + j] + bih_sl[j];
      float giz = gi_cur[b * 192 + 64 + j] + bih_sl[64 + j];
      float gin = gi_cur[b * 192 + 128 + j] + bih_sl[128 + j];
      float ghr = gh_sl[b * 192 + j] + bhh_sl[j];
      float ghz = gh_sl[b * 192 + 64 + j] + bhh_sl[64 + j];
      float ghn = gh_sl[b * 192 + 128 + j] + bhh_sl[128 + j];
      float r = 1.f / (1.f + expf(-(gir + ghr)));
      float z = 1.f / (1.f + expf(-(giz + ghz)));
      float n = tanhf(gin + r * ghn);
      hc_sl[(b << 6) + j] = (1.f - z) * n + z * hp_sl[(b << 6) + j];
    } else if (tid >= 256 && tid < 352 && t + 1 < S_) {
      int idx = tid - 256;  // 0..95
      int b = idx / 48, rr = idx % 48;
      int gate = rr >> 4, pos = rr & 15;
      float4 v = *(const float4*)(gi_all +
          ((size_t)(g * NB + b) * S_ + (t + 1)) * G3H + (gate << 9) + d0 +
          (pos << 2));
      *(float4*)(gi2 + (((t + 1) & 1) * 2 + b) * 192 + (gate << 6) +
                 (pos << 2)) = v;
    }
    __syncthreads();

    // ---- B: dist partials over 64 dims -> packed sign-tagged stores ----
    {
      int b = tid >> 8;              // 0..1
      int sub = tid & 255;
      int k4 = sub >> 2;             // float4-of-k index 0..63
      int jq = sub & 3;              // j quarter (16 dims each)
      const float* hb = hc_sl + (b << 6) + (jq << 4);
      const float4* sp = (const float4*)(s_T + ((jq << 4) * 256) + (k4 << 2));
      float ax = 0.f, ay = 0.f, az = 0.f, aw = 0.f;
#pragma unroll
      for (int jj = 0; jj < 16; ++jj) {
        float4 s4 = sp[jj * 64];
        float hv = hb[jj];
        float e;
        e = hv - s4.x; ax += e * e;
        e = hv - s4.y; ay += e * e;
        e = hv - s4.z; az += e * e;
        e = hv - s4.w; aw += e * e;
      }
      ax += __shfl_xor(ax, 1); ax += __shfl_xor(ax, 2);
      ay += __shfl_xor(ay, 1); ay += __shfl_xor(ay, 2);
      az += __shfl_xor(az, 1); az += __shfl_xor(az, 2);
      aw += __shfl_xor(aw, 1); aw += __shfl_xor(aw, 2);
      if (jq == 0) {
        unsigned long long* dst =
            pks + ((((size_t)(g * NB + b) << 3) + cu) << 7) + (k4 << 1);
        tstore(dst + 0, pk_pack(ax, ay, sb));
        tstore(dst + 1, pk_pack(az, aw, sb));
      }
    }

    // ---- C: poll 8 sources, split by source-half over all 512 threads ----
    {
      int b = (tid >> 7) & 1, wp = tid & 127;
      int s0 = (tid < 256) ? 0 : 4;  // source half
      const unsigned long long* base =
          pks + (((size_t)(g * NB + b) << 3) << 7) + ((size_t)s0 << 7) + wp;
      unsigned long long wd[4];
#pragma unroll
      for (int s = 0; s < 4; ++s) wd[s] = tload(base + (s << 7));
#pragma unroll
      for (int s = 0; s < 4; ++s) {
        int it = 0;
        while ((wd[s] & SGNMASK) != expect && ++it < SPIN_MAX)
          wd[s] = tload(base + (s << 7));
      }
      float dlo = 0.f, dhi = 0.f;
#pragma unroll
      for (int s = 0; s < 4; ++s) {
        dlo += __uint_as_float((unsigned)(wd[s] & 0x7fffffffu));
        dhi += __uint_as_float((unsigned)((wd[s] >> 32) & 0x7fffffffu));
      }
      float* dd = (tid < 256) ? d_a : d_b;
      dd[(b << 8) + (wp << 1) + 0] = dlo;
      dd[(b << 8) + (wp << 1) + 1] = dhi;
    }
    __syncthreads();

    // ---- D: softmax (waves 0-1, wave = batch) -> p_ch chunked + probs ----
    if (wv < NB) {
      int b = wv;
      const float* da = d_a + (b << 8);
      const float* db = d_b + (b << 8);
      float dd0 = da[lane] + db[lane];
      float dd1 = da[lane + 64] + db[lane + 64];
      float dd2 = da[lane + 128] + db[lane + 128];
      float dd3 = da[lane + 192] + db[lane + 192];
      float mn = fminf(fminf(dd0, dd1), fminf(dd2, dd3));
#pragma unroll
      for (int off = 32; off >= 1; off >>= 1) mn = fminf(mn, __shfl_xor(mn, off));
      float e0 = expf(mn - dd0), e1 = expf(mn - dd1), e2 = expf(mn - dd2),
            e3 = expf(mn - dd3);
      float s = (e0 + e1) + (e2 + e3);
#pragma unroll
      for (int off = 32; off >= 1; off >>= 1) s += __shfl_xor(s, off);
      float inv = 1.f / s;
      e0 *= inv; e1 *= inv; e2 *= inv; e3 *= inv;
      int hi = lane >> 4, lo = lane & 15;
      p_ch[(b * 16 + hi + 0) * 20 + lo] = e0;
      p_ch[(b * 16 + hi + 4) * 20 + lo] = e1;
      p_ch[(b * 16 + hi + 8) * 20 + lo] = e2;
      p_ch[(b * 16 + hi + 12) * 20 + lo] = e3;
      if (cu == 0) {
        float* pr = probs + (((size_t)(g * NB + b) * S_ + t) << 8);
        pr[lane] = e0; pr[lane + 64] = e1; pr[lane + 128] = e2;
        pr[lane + 192] = e3;
      }
    }
    __syncthreads();

    // ---- E: gh(t+1) = p @ SWT^T (all threads, half-split rows) ----
    if (t + 1 < S_) {
      float acc[2][6];
#pragma unroll
      for (int b = 0; b < 2; ++b) {
        const float4* xp = (const float4*)(p_ch + (b * 16 + kseg) * 20);
        float4 x0 = xp[0], x1 = xp[1], x2 = xp[2], x3 = xp[3];
#pragma unroll
        for (int i = 0; i < 6; ++i)
          acc[b][i] = dot4(w[i][0], x0) + dot4(w[i][1], x1) +
                      dot4(w[i][2], x2) + dot4(w[i][3], x3);
      }
#pragma unroll
      for (int b = 0; b < 2; ++b)
#pragma unroll
        for (int i = 0; i < 6; ++i) {
          float v = acc[b][i];
          v += __shfl_xor(v, 1); v += __shfl_xor(v, 2);
          v += __shfl_xor(v, 4); v += __shfl_xor(v, 8);
          acc[b][i] = v;
        }
      if (kseg == 0) {
#pragma unroll
        for (int b = 0; b < 2; ++b)
#pragma unroll
          for (int i = 0; i < 6; ++i)
            gh_sl[b * 192 + half * 96 + rowblk * 6 + i] = acc[b][i];
      }
    }

    // ---- F: h_new (all 512 threads: b, j, kq) ----
    {
      int b = tid >> 8, sub2 = tid & 255;
      int j = sub2 >> 2, kq = sub2 & 3;
      float a = 0.f;
#pragma unroll
      for (int i = 0; i < 16; ++i) {
        int c = kq + (i << 2);  // float4-of-k chunk 0..63
        float4 p4 = *(const float4*)(p_ch + (b * 16 + (c >> 2)) * 20 +
                                     ((c & 3) << 2));
        int k = c << 2;
        a += p4.x * s_sl[(k + 0) * 68 + j] + p4.y * s_sl[(k + 1) * 68 + j] +
             p4.z * s_sl[(k + 2) * 68 + j] + p4.w * s_sl[(k + 3) * 68 + j];
      }
      a += __shfl_xor(a, 1);
      a += __shfl_xor(a, 2);
      if (kq == 0) {
        hp_sl[(b << 6) + j] = a;
        out[(((size_t)(g * NB + b) * S_ + t) << 9) + d0 + j] = a;
      }
    }
    __syncthreads();
  }

  // ---- final hidden state ----
  if (tid < 128) {
    int b = tid >> 6, j = tid & 63;
    hn[((size_t)(g * NB + b) << 9) + d0 + j] = hp_sl[(b << 6) + j];
  }
}

// ---------------------------------------------------------------------------
extern "C" void kernel_launch(void* const* d_in, const int* in_sizes, int n_in,
                              void* d_out, int out_size, void* d_ws,
                              size_t ws_size, hipStream_t stream) {
  const float* input = (const float*)d_in[0];
  const float* h0 = (const float*)d_in[1];
  const float* W_ih = (const float*)d_in[2];
  const float* W_hh = (const float*)d_in[3];
  const float* bias_ih = (const float*)d_in[4];
  const float* bias_hh = (const float*)d_in[5];
  const float* states = (const float*)d_in[6];
  float* out = (float*)d_out;

  char* ws = (char*)d_ws;
  float* SWT = (float*)(ws + WS_SWT);
  float* Gh0 = (float*)(ws + WS_GH0);
  unsigned long long* pk = (unsigned long long*)(ws + WS_PK);
  float* gi_all = (float*)(ws + WS_GI);

  // 0x80 bytes -> every packed float negative -> never matches the expected
  // sign pattern at t=0/1; kills cross-replay staleness.
  (void)hipMemsetAsync(ws + WS_PK, 0x80, WS_PK_SZ, stream);
  kernel_swt<<<G3H / 8, 256, 0, stream>>>(W_hh, states, SWT);
  kernel_gh0<<<B_, 256, 0, stream>>>(W_hh, h0, Gh0);
  kernel_gi<<<dim3(S_ / 16, B_), 256, 0, stream>>>(input, W_ih, gi_all);

  (void)hipFuncSetAttribute(reinterpret_cast<const void*>(srrnn_main),
                            hipFuncAttributeMaxDynamicSharedMemorySize,
                            SMEM_BYTES);
  srrnn_main<<<NGRP * GCU, TPB, SMEM_BYTES, stream>>>(
      gi_all, h0, bias_ih, bias_hh, states, SWT, Gh0, pk,
      out, out + OUT_OFF_HN, out + OUT_OFF_P);
}

// Round 18
// 4085.282 us; speedup vs baseline: 1.3707x; 1.1813x over previous
//
#include <hip/hip_runtime.h>
#include <math.h>

// ---------------------------------------------------------------------------
// SRRNN: state-regularized GRU.  B=64, S=512, I=256, H=512, K=256, TEMP=1.
//
// FINAL (= Round 12, the best measured configuration: 4077 us).
//  - 16 groups x 16 CUs, NB=4 batches/group, DPC=32 dims/CU.
//  - Register-resident weight slices: wi[6][4] + wh[6][4] = 24 float4/thread
//    (the allocator-proven size; 48 float4 is silently refused -> L2
//    restream, proven in R8/R14/R16).
//  - ONE MALL hop per step: every CU full-replicates the 16-source dist
//    reduce + softmax locally. Sign-bit validity protocol: communicated
//    values are >= 0, so the sign bit carries freshness; 2 slots (t&1),
//    expected sign (t>>1)&1, 2 f32 packed per 64-bit atomic word,
//    memset(0x80) per launch (stale = negative = never matches at t=0/1).
//    Distance-2 slot reuse is self-synchronizing.
//  - Structural floor analysis (R13-R17 all failed to beat this): per-step
//    cost ~= store-drain + cross-XCD observe + serial compute chain ~ 8us,
//    latency-bound on the inherent sequential x communication structure.
// ---------------------------------------------------------------------------

#define B_ 64
#define S_ 512
#define I_ 256
#define H_ 512
#define K_ 256
#define G3H 1536
#define NGRP 16
#define GCU 16
#define NB 4
#define DPC 32     // dims per CU
#define TPB 512
#define SPIN_MAX (1 << 15)

// workspace layout (bytes)
#define WS_SWT 4096
#define WS_SWT_SZ (G3H * K_ * 4)                       // 1572864
#define WS_GH0 (WS_SWT + WS_SWT_SZ)
#define WS_GH0_SZ (B_ * G3H * 4)                       // 393216
#define WS_PK (WS_GH0 + WS_GH0_SZ)                     // 1970176 (8B aligned)
#define WS_PK_SZ (2 * NGRP * NB * GCU * 128 * 8)       // 2097152

// LDS float offsets
#define L_ST 0               // s_T[32][256]   j-major
#define L_SSL 8192           // s_sl[256][36]  k-major
#define L_XCH 17408          // x_ch [4][16][20]
#define L_PCH 18688          // p_ch [4][16][20]
#define L_GI 19968           // gi_sl [4][96]
#define L_GH 20352           // gh_sl [4][96]
#define L_HC 20736           // hc_sl [4][32]
#define L_HP 20864           // hp_sl [4][32]
#define L_BIH 20992          // [96]
#define L_BHH 21088          // [96]
#define L_D 21184            // d_sl [4][256]
#define SMEM_BYTES 90112     // >80KB -> 1 block/CU

#define OUT_OFF_HN (B_ * S_ * H_)
#define OUT_OFF_P (OUT_OFF_HN + B_ * H_)

#define AGENT __HIP_MEMORY_SCOPE_AGENT
#define RLX __ATOMIC_RELAXED
#define SGNMASK 0x8000000080000000ull

// ---------------------------------------------------------------------------
__global__ void kernel_swt(const float* __restrict__ Whh,
                           const float* __restrict__ states,
                           float* __restrict__ SWT) {
  int r0 = blockIdx.x * 8;
  int k = threadIdx.x;  // 0..255
  const float* sr = states + (size_t)k * H_;
  float acc[8];
#pragma unroll
  for (int q = 0; q < 8; ++q) acc[q] = 0.f;
  for (int j = 0; j < H_; ++j) {
    float sv = sr[j];
#pragma unroll
    for (int q = 0; q < 8; ++q) acc[q] += Whh[(size_t)(r0 + q) * H_ + j] * sv;
  }
#pragma unroll
  for (int q = 0; q < 8; ++q) SWT[(size_t)(r0 + q) * K_ + k] = acc[q];
}

__global__ void kernel_gh0(const float* __restrict__ Whh,
                           const float* __restrict__ h0,
                           float* __restrict__ Gh0) {
  int b = blockIdx.x;
  int tid = threadIdx.x;  // 256
  __shared__ float h[H_];
  for (int e = tid; e < H_; e += 256) h[e] = h0[(size_t)b * H_ + e];
  __syncthreads();
  for (int r = tid; r < G3H; r += 256) {
    const float* wr = Whh + (size_t)r * H_;
    float acc = 0.f;
    for (int j = 0; j < H_; ++j) acc += wr[j] * h[j];
    Gh0[(size_t)b * G3H + r] = acc;
  }
}

// ---------------------------------------------------------------------------
__device__ __forceinline__ float dot4(float4 a, float4 b) {
  return a.x * b.x + a.y * b.y + a.z * b.z + a.w * b.w;
}
__device__ __forceinline__ unsigned long long pk_pack(float lo, float hi,
                                                      unsigned sb) {
  return ((unsigned long long)(__float_as_uint(hi) | sb) << 32) |
         (unsigned long long)(__float_as_uint(lo) | sb);
}
__device__ __forceinline__ unsigned long long tload(
    const unsigned long long* p) {
  return __hip_atomic_load(p, RLX, AGENT);
}
__device__ __forceinline__ void tstore(unsigned long long* p,
                                       unsigned long long w) {
  __hip_atomic_store(p, w, RLX, AGENT);
}

__global__ __launch_bounds__(TPB, 2) void srrnn_main(
    const float* __restrict__ input, const float* __restrict__ h0,
    const float* __restrict__ W_ih, const float* __restrict__ bias_ih,
    const float* __restrict__ bias_hh, const float* __restrict__ states,
    const float* __restrict__ SWT, const float* __restrict__ Gh0,
    unsigned long long* __restrict__ pk,
    float* __restrict__ out, float* __restrict__ hn,
    float* __restrict__ probs) {
  const int tid = threadIdx.x;
  const int g = blockIdx.x >> 4;   // group 0..15
  const int cu = blockIdx.x & 15;  // CU in group
  const int d0 = cu << 5;          // owned dim base (32 dims)

  extern __shared__ float smem[];
  float* s_T = smem + L_ST;        // [j][256]
  float* s_sl = smem + L_SSL;      // [k][36]
  float* x_ch = smem + L_XCH;      // [4][16][20]
  float* p_ch = smem + L_PCH;      // [4][16][20]
  float* gi_sl = smem + L_GI;
  float* gh_sl = smem + L_GH;
  float* hc_sl = smem + L_HC;
  float* hp_sl = smem + L_HP;
  float* bih_sl = smem + L_BIH;
  float* bhh_sl = smem + L_BHH;
  float* d_sl = smem + L_D;

  const int wv = tid >> 6, lane = tid & 63;
  const int rowblk = tid >> 4, kseg = tid & 15;  // GEMM org: 32 rowblk x 16 kseg

  // ---- setup ----
  for (int e = tid; e < K_ * DPC; e += TPB) {
    int k = e >> 5, j = e & 31;
    float v = states[((size_t)k << 9) + d0 + j];
    s_T[j * 256 + k] = v;
    s_sl[k * 36 + j] = v;
  }
  if (tid < 96) {
    int grow = ((tid >> 5) << 9) + d0 + (tid & 31);
    bih_sl[tid] = bias_ih[grow];
    bhh_sl[tid] = bias_hh[grow];
  }
  if (tid < 128) {
    int b = tid >> 5, j = tid & 31;
    hp_sl[(b << 5) + j] = h0[((size_t)(g * NB + b) << 9) + d0 + j];
  }
  if (tid < 384) {
    int b = tid / 96, r = tid % 96;
    int grow = ((r >> 5) << 9) + d0 + (r & 31);
    gh_sl[b * 96 + r] = Gh0[(size_t)(g * NB + b) * G3H + grow];
  }
  // weight fragments -> registers: 3 rows x 16 k per thread, both matrices
  float4 wi[3][4], wh[3][4];
#pragma unroll
  for (int i = 0; i < 3; ++i) {
    int r = rowblk * 3 + i;  // 0..95
    int grow = ((r >> 5) << 9) + d0 + (r & 31);
    const float4* si = (const float4*)(W_ih + (size_t)grow * K_ + (kseg << 4));
    const float4* sh = (const float4*)(SWT + (size_t)grow * K_ + (kseg << 4));
    wi[i][0] = si[0]; wi[i][1] = si[1]; wi[i][2] = si[2]; wi[i][3] = si[3];
    wh[i][0] = sh[0]; wh[i][1] = sh[1]; wh[i][2] = sh[2]; wh[i][3] = sh[3];
  }
  __syncthreads();

  // ---- pre-loop: stage x(0) chunked, gi(0) ----
  if (tid < 256) {
    int b = tid >> 6, c = tid & 63;
    float4 v = *((const float4*)(input + ((size_t)(g * NB + b) * S_) * I_) + c);
    *(float4*)(x_ch + (b * 16 + (c >> 2)) * 20 + ((c & 3) << 2)) = v;
  }
  __syncthreads();
  {
    float acc[4][3] = {};
#pragma unroll
    for (int b = 0; b < 4; ++b) {
      const float4* xp = (const float4*)(x_ch + (b * 16 + kseg) * 20);
#pragma unroll
      for (int c = 0; c < 4; ++c) {
        float4 xv = xp[c];
#pragma unroll
        for (int i = 0; i < 3; ++i) acc[b][i] += dot4(wi[i][c], xv);
      }
    }
#pragma unroll
    for (int b = 0; b < 4; ++b)
#pragma unroll
      for (int i = 0; i < 3; ++i) {
        float v = acc[b][i];
        v += __shfl_xor(v, 1); v += __shfl_xor(v, 2);
        v += __shfl_xor(v, 4); v += __shfl_xor(v, 8);
        acc[b][i] = v;
      }
    if (kseg == 0) {
#pragma unroll
      for (int b = 0; b < 4; ++b)
#pragma unroll
        for (int i = 0; i < 3; ++i) gi_sl[b * 96 + rowblk * 3 + i] = acc[b][i];
    }
  }
  __syncthreads();

  for (int t = 0; t < S_; ++t) {
    const unsigned sb = (unsigned)((t >> 1) & 1) << 31;
    const unsigned long long expect =
        ((unsigned long long)sb << 32) | (unsigned long long)sb;
    unsigned long long* pks = pk + ((size_t)(t & 1) << 17);  // slot base

    // ---- A: gates + h_cand over owned 32 dims ----
    if (tid < 128) {
      int b = tid >> 5, j = tid & 31;
      float gir = gi_sl[b * 96 + j] + bih_sl[j];
      float giz = gi_sl[b * 96 + 32 + j] + bih_sl[32 + j];
      float gin = gi_sl[b * 96 + 64 + j] + bih_sl[64 + j];
      float ghr = gh_sl[b * 96 + j] + bhh_sl[j];
      float ghz = gh_sl[b * 96 + 32 + j] + bhh_sl[32 + j];
      float ghn = gh_sl[b * 96 + 64 + j] + bhh_sl[64 + j];
      float r = 1.f / (1.f + expf(-(gir + ghr)));
      float z = 1.f / (1.f + expf(-(giz + ghz)));
      float n = tanhf(gin + r * ghn);
      hc_sl[(b << 5) + j] = (1.f - z) * n + z * hp_sl[(b << 5) + j];
    }
    __syncthreads();

    // ---- B: dist partials (vectorized) -> packed sign-tagged stores ----
    {
      int b = tid >> 7;              // 0..3
      int sub = tid & 127;
      int k4 = sub >> 1;             // float4-of-k index 0..63
      int jh = sub & 1;              // j-half
      const float* hb = hc_sl + (b << 5) + (jh << 4);
      const float4* sp = (const float4*)(s_T + ((jh << 4) * 256) + (k4 << 2));
      float ax = 0.f, ay = 0.f, az = 0.f, aw = 0.f;
#pragma unroll
      for (int jj = 0; jj < 16; ++jj) {
        float4 s4 = sp[jj * 64];
        float hv = hb[jj];
        float e;
        e = hv - s4.x; ax += e * e;
        e = hv - s4.y; ay += e * e;
        e = hv - s4.z; az += e * e;
        e = hv - s4.w; aw += e * e;
      }
      ax += __shfl_xor(ax, 1);
      ay += __shfl_xor(ay, 1);
      az += __shfl_xor(az, 1);
      aw += __shfl_xor(aw, 1);
      if (jh == 0) {
        unsigned long long* dst =
            pks + ((((size_t)(g * NB + b) * GCU) + cu) << 7) + (k4 << 1);
        tstore(dst + 0, pk_pack(ax, ay, sb));
        tstore(dst + 1, pk_pack(az, aw, sb));
      }
    }

    // ---- C (shadow): stage x(t+1) + gi(t+1) GEMM (register W_ih) ----
    if (t + 1 < S_) {
      if (tid < 256) {
        int b = tid >> 6, c = tid & 63;
        float4 v = *((const float4*)(input +
                     ((size_t)(g * NB + b) * S_ + (t + 1)) * I_) + c);
        *(float4*)(x_ch + (b * 16 + (c >> 2)) * 20 + ((c & 3) << 2)) = v;
      }
      __syncthreads();
      {
        float acc[4][3] = {};
#pragma unroll
        for (int b = 0; b < 4; ++b) {
          const float4* xp = (const float4*)(x_ch + (b * 16 + kseg) * 20);
#pragma unroll
          for (int c = 0; c < 4; ++c) {
            float4 xv = xp[c];
#pragma unroll
            for (int i = 0; i < 3; ++i) acc[b][i] += dot4(wi[i][c], xv);
          }
        }
#pragma unroll
        for (int b = 0; b < 4; ++b)
#pragma unroll
          for (int i = 0; i < 3; ++i) {
            float v = acc[b][i];
            v += __shfl_xor(v, 1); v += __shfl_xor(v, 2);
            v += __shfl_xor(v, 4); v += __shfl_xor(v, 8);
            acc[b][i] = v;
          }
        if (kseg == 0) {
#pragma unroll
          for (int b = 0; b < 4; ++b)
#pragma unroll
            for (int i = 0; i < 3; ++i)
              gi_sl[b * 96 + rowblk * 3 + i] = acc[b][i];
        }
      }
    }

    // ---- P: poll all 16 CUs' packed partials, reduce -> d_sl ----
    {
      int b = tid >> 7, kp = tid & 127;  // word index
      const unsigned long long* base =
          pks + (((size_t)(g * NB + b) * GCU) << 7) + kp;
      unsigned long long w[16];
#pragma unroll
      for (int s = 0; s < 16; ++s) w[s] = tload(base + (s << 7));
#pragma unroll
      for (int s = 0; s < 16; ++s) {
        int it = 0;
        while ((w[s] & SGNMASK) != expect && ++it < SPIN_MAX)
          w[s] = tload(base + (s << 7));
      }
      float dlo = 0.f, dhi = 0.f;
#pragma unroll
      for (int s = 0; s < 16; ++s) {
        dlo += __uint_as_float((unsigned)(w[s] & 0x7fffffffu));
        dhi += __uint_as_float((unsigned)((w[s] >> 32) & 0x7fffffffu));
      }
      d_sl[(b << 8) + (kp << 1) + 0] = dlo;
      d_sl[(b << 8) + (kp << 1) + 1] = dhi;
    }
    __syncthreads();

    // ---- G: softmax (waves 0-3, wave = batch) -> p_ch chunked + probs ----
    if (wv < NB) {
      int b = wv;
      const float* db = d_sl + (b << 8);
      float dd0 = db[lane], dd1 = db[lane + 64], dd2 = db[lane + 128],
            dd3 = db[lane + 192];
      float mn = fminf(fminf(dd0, dd1), fminf(dd2, dd3));
#pragma unroll
      for (int off = 32; off >= 1; off >>= 1) mn = fminf(mn, __shfl_xor(mn, off));
      float e0 = expf(mn - dd0), e1 = expf(mn - dd1), e2 = expf(mn - dd2),
            e3 = expf(mn - dd3);
      float s = (e0 + e1) + (e2 + e3);
#pragma unroll
      for (int off = 32; off >= 1; off >>= 1) s += __shfl_xor(s, off);
      float inv = 1.f / s;
      e0 *= inv; e1 *= inv; e2 *= inv; e3 *= inv;
      int hi = lane >> 4, lo = lane & 15;
      p_ch[(b * 16 + hi + 0) * 20 + lo] = e0;
      p_ch[(b * 16 + hi + 4) * 20 + lo] = e1;
      p_ch[(b * 16 + hi + 8) * 20 + lo] = e2;
      p_ch[(b * 16 + hi + 12) * 20 + lo] = e3;
      if (cu == 0) {
        float* pr = probs + (((size_t)(g * NB + b) * S_ + t) << 8);
        pr[lane] = e0; pr[lane + 64] = e1; pr[lane + 128] = e2;
        pr[lane + 192] = e3;
      }
    }
    __syncthreads();

    // ---- H1: gh(t+1) = p @ SWT^T from registers; p from chunked layout ----
    if (t + 1 < S_) {
      float acc[4][3] = {};
#pragma unroll
      for (int b = 0; b < 4; ++b) {
        const float4* xp = (const float4*)(p_ch + (b * 16 + kseg) * 20);
#pragma unroll
        for (int c = 0; c < 4; ++c) {
          float4 xv = xp[c];
#pragma unroll
          for (int i = 0; i < 3; ++i) acc[b][i] += dot4(wh[i][c], xv);
        }
      }
#pragma unroll
      for (int b = 0; b < 4; ++b)
#pragma unroll
        for (int i = 0; i < 3; ++i) {
          float v = acc[b][i];
          v += __shfl_xor(v, 1); v += __shfl_xor(v, 2);
          v += __shfl_xor(v, 4); v += __shfl_xor(v, 8);
          acc[b][i] = v;
        }
      if (kseg == 0) {
#pragma unroll
        for (int b = 0; b < 4; ++b)
#pragma unroll
          for (int i = 0; i < 3; ++i)
            gh_sl[b * 96 + rowblk * 3 + i] = acc[b][i];
      }
    }

    // ---- H2: h_new. thread = (b, j, kq) ----
    {
      int b = tid >> 7, j = (tid >> 2) & 31, kq = tid & 3;
      float a = 0.f;
#pragma unroll
      for (int i = 0; i < 16; ++i) {
        float4 p4 = *(const float4*)(p_ch + (b * 16 + i) * 20 + (kq << 2));
        int k = (i << 4) + (kq << 2);
        a += p4.x * s_sl[(k + 0) * 36 + j] + p4.y * s_sl[(k + 1) * 36 + j] +
             p4.z * s_sl[(k + 2) * 36 + j] + p4.w * s_sl[(k + 3) * 36 + j];
      }
      a += __shfl_xor(a, 1);
      a += __shfl_xor(a, 2);
      if (kq == 0) {
        hp_sl[(b << 5) + j] = a;
        out[(((size_t)(g * NB + b) * S_ + t) << 9) + d0 + j] = a;
      }
    }
    __syncthreads();
  }

  // ---- final hidden state ----
  if (tid < 128) {
    int b = tid >> 5, j = tid & 31;
    hn[((size_t)(g * NB + b) << 9) + d0 + j] = hp_sl[(b << 5) + j];
  }
}

// ---------------------------------------------------------------------------
extern "C" void kernel_launch(void* const* d_in, const int* in_sizes, int n_in,
                              void* d_out, int out_size, void* d_ws,
                              size_t ws_size, hipStream_t stream) {
  const float* input = (const float*)d_in[0];
  const float* h0 = (const float*)d_in[1];
  const float* W_ih = (const float*)d_in[2];
  const float* W_hh = (const float*)d_in[3];
  const float* bias_ih = (const float*)d_in[4];
  const float* bias_hh = (const float*)d_in[5];
  const float* states = (const float*)d_in[6];
  float* out = (float*)d_out;

  char* ws = (char*)d_ws;
  float* SWT = (float*)(ws + WS_SWT);
  float* Gh0 = (float*)(ws + WS_GH0);
  unsigned long long* pk = (unsigned long long*)(ws + WS_PK);

  // 0x80 bytes -> every packed float is negative -> never matches the
  // expected (non-stale) sign pattern at t=0/1; kills cross-replay staleness.
  (void)hipMemsetAsync(ws + WS_PK, 0x80, WS_PK_SZ, stream);
  kernel_swt<<<G3H / 8, 256, 0, stream>>>(W_hh, states, SWT);
  kernel_gh0<<<B_, 256, 0, stream>>>(W_hh, h0, Gh0);

  (void)hipFuncSetAttribute(reinterpret_cast<const void*>(srrnn_main),
                            hipFuncAttributeMaxDynamicSharedMemorySize,
                            SMEM_BYTES);
  srrnn_main<<<NGRP * GCU, TPB, SMEM_BYTES, stream>>>(
      input, h0, W_ih, bias_ih, bias_hh, states, SWT, Gh0, pk,
      out, out + OUT_OFF_HN, out + OUT_OFF_P);
}